// Round 1
// baseline (569.233 us; speedup 1.0000x reference)
//
#include <hip/hip_runtime.h>
#include <hip/hip_bf16.h>

// Problem constants
#define B_SZ 8192
#define D_SZ 512
#define K_SZ 4096
#define L_SZ 16
#define M_ALL (B_SZ + K_SZ)   // 12288 rows: targets stacked over codebook

typedef __attribute__((ext_vector_type(8))) short short8v;   // 8 bf16 = 4 VGPRs
typedef __attribute__((ext_vector_type(4))) float f32x4;

// ---------------------------------------------------------------------------
// Kernel 1: cast targets+codebook (fp32) into one stacked bf16 matrix [12288 x 512]
// ---------------------------------------------------------------------------
__global__ void cast_bf16_kernel(const float* __restrict__ targets,
                                 const float* __restrict__ codebook,
                                 __hip_bfloat16* __restrict__ abf) {
    int idx = blockIdx.x * blockDim.x + threadIdx.x;      // group of 4 elements
    const int total4 = (M_ALL * D_SZ) / 4;
    if (idx >= total4) return;
    int base = idx * 4;
    const float* src = (base < B_SZ * D_SZ) ? (targets + base)
                                            : (codebook + (base - B_SZ * D_SZ));
    float4 v = *(const float4*)src;
    abf[base + 0] = __float2bfloat16(v.x);
    abf[base + 1] = __float2bfloat16(v.y);
    abf[base + 2] = __float2bfloat16(v.z);
    abf[base + 3] = __float2bfloat16(v.w);
}

// ---------------------------------------------------------------------------
// Kernel 2: S = A * B^T  (A [M x 512] bf16 row-major, B [4096 x 512] bf16 row-major)
// S [M x 4096] fp32. 128x128 tile, 256 threads (4 waves, 2x2), 4x4 16x16x32 MFMAs/wave.
// ---------------------------------------------------------------------------
#define BM 128
#define BN 128
#define BK 32
#define LDSS 40   // bf16 elems/row: 80B stride, 16B-aligned, 2-way-max bank aliasing

__global__ __launch_bounds__(256, 2)
void gemm_bt_kernel(const __hip_bfloat16* __restrict__ A,
                    const __hip_bfloat16* __restrict__ Bm,
                    float* __restrict__ C) {
    __shared__ short As[BM * LDSS];
    __shared__ short Bs[BN * LDSS];
    const int tid  = threadIdx.x;
    const int bm   = blockIdx.y * BM;
    const int bn   = blockIdx.x * BN;
    const int wave = tid >> 6, lane = tid & 63;
    const int wm = (wave & 1) * 64, wn = (wave >> 1) * 64;
    const int row16 = lane & 15, quad = lane >> 4;
    const int koff = quad * 8;

    f32x4 acc[4][4] = {};

    const int srow = tid >> 1;           // 0..127
    const int scol = (tid & 1) * 16;     // 0 or 16 (bf16 elems)
    const short* Ag = (const short*)A;
    const short* Bg = (const short*)Bm;

    for (int k0 = 0; k0 < D_SZ; k0 += BK) {
        short8v a0 = *(const short8v*)(Ag + (size_t)(bm + srow) * D_SZ + k0 + scol);
        short8v a1 = *(const short8v*)(Ag + (size_t)(bm + srow) * D_SZ + k0 + scol + 8);
        short8v b0 = *(const short8v*)(Bg + (size_t)(bn + srow) * D_SZ + k0 + scol);
        short8v b1 = *(const short8v*)(Bg + (size_t)(bn + srow) * D_SZ + k0 + scol + 8);
        __syncthreads();   // protect previous iteration's fragment reads
        *(short8v*)(As + srow * LDSS + scol)     = a0;
        *(short8v*)(As + srow * LDSS + scol + 8) = a1;
        *(short8v*)(Bs + srow * LDSS + scol)     = b0;
        *(short8v*)(Bs + srow * LDSS + scol + 8) = b1;
        __syncthreads();

        short8v af[4], bf[4];
#pragma unroll
        for (int i = 0; i < 4; i++)
            af[i] = *(const short8v*)(As + (wm + i * 16 + row16) * LDSS + koff);
#pragma unroll
        for (int j = 0; j < 4; j++)
            bf[j] = *(const short8v*)(Bs + (wn + j * 16 + row16) * LDSS + koff);
#pragma unroll
        for (int i = 0; i < 4; i++)
#pragma unroll
            for (int j = 0; j < 4; j++)
                acc[i][j] = __builtin_amdgcn_mfma_f32_16x16x32_bf16(af[i], bf[j], acc[i][j], 0, 0, 0);
    }

    // C/D layout: col = lane&15, row = quad*4 + reg  [m89/m91 verified]
#pragma unroll
    for (int i = 0; i < 4; i++) {
        int grow = bm + wm + i * 16 + quad * 4;
#pragma unroll
        for (int j = 0; j < 4; j++) {
            int gcol = bn + wn + j * 16 + row16;
#pragma unroll
            for (int r = 0; r < 4; r++)
                C[(size_t)(grow + r) * K_SZ + gcol] = acc[i][j][r];
        }
    }
}

// ---------------------------------------------------------------------------
// Kernel 3: pursuit. One block per batch row. g (fp32 approx scores) in LDS,
// residual (fp64 exact) in LDS. Per step: approx argmax -> candidates within
// margin -> exact fp64 rescore -> exact update.
// ---------------------------------------------------------------------------
#define MAXC 64
#define MARGIN 2.0f

__global__ __launch_bounds__(256)
void pursuit_kernel(const float* __restrict__ targets,
                    const float* __restrict__ codebook,
                    const float* __restrict__ S,     // [12288 x 4096]; rows >=8192 are Gram
                    float* __restrict__ out) {
    const int b = blockIdx.x;
    const int tid = threadIdx.x;
    const int lane = tid & 63, wave = tid >> 6;

    __shared__ float  g[K_SZ];
    __shared__ double rres[D_SZ];
    __shared__ double redD[4];
    __shared__ float  redF[4];
    __shared__ int    cand_k[MAXC];
    __shared__ double cand_v[MAXC];
    __shared__ int    ncand;
    __shared__ int    s_best;
    __shared__ double s_sd;

    // load approx scores
    const float* g0row = S + (size_t)b * K_SZ;
#pragma unroll
    for (int j = 0; j < K_SZ / 256; j++)
        g[tid + 256 * j] = g0row[tid + 256 * j];

    // residual = target (fp64), target_norm^2
    double loc = 0.0;
    for (int i = tid; i < D_SZ; i += 256) {
        double v = (double)targets[(size_t)b * D_SZ + i];
        rres[i] = v;
        loc += v * v;
    }
#pragma unroll
    for (int o = 32; o > 0; o >>= 1) loc += __shfl_down(loc, o, 64);
    if (lane == 0) redD[wave] = loc;
    __syncthreads();
    const double tn2 = redD[0] + redD[1] + redD[2] + redD[3];
    double rn2 = tn2;
    __syncthreads();

    float* out_seq  = out;
    float* out_mask = out + (size_t)B_SZ * L_SZ;
    float* out_res  = out + (size_t)2 * B_SZ * L_SZ;

    double decay = 1.0;
    for (int t = 0; t < L_SZ; t++) {
        decay *= 0.95;
        bool active = (sqrt(rn2) >= 0.01) && (sqrt(tn2) >= 1e-8);
        if (!active) {
            if (tid == 0) {
                out_seq[(size_t)b * L_SZ + t]  = 0.0f;
                out_mask[(size_t)b * L_SZ + t] = 0.0f;
            }
            continue;   // uniform branch; residual & scores frozen
        }

        // approx max |g|
        float m = 0.0f;
#pragma unroll
        for (int j = 0; j < K_SZ / 256; j++)
            m = fmaxf(m, fabsf(g[tid + 256 * j]));
#pragma unroll
        for (int o = 32; o > 0; o >>= 1) m = fmaxf(m, __shfl_down(m, o, 64));
        if (lane == 0) redF[wave] = m;
        if (tid == 0) ncand = 0;
        __syncthreads();
        float M = fmaxf(fmaxf(redF[0], redF[1]), fmaxf(redF[2], redF[3]));
        float thr = M - MARGIN;
        __syncthreads();

        // candidate collection
#pragma unroll
        for (int j = 0; j < K_SZ / 256; j++) {
            int k = tid + 256 * j;
            if (fabsf(g[k]) >= thr) {
                int p = atomicAdd(&ncand, 1);
                if (p < MAXC) cand_k[p] = k;
            }
        }
        __syncthreads();
        int nc = min(ncand, MAXC);

        // exact fp64 rescore: one wave per candidate
        for (int cb = 0; cb < nc; cb += 4) {
            int ci = cb + wave;
            if (ci < nc) {
                int k = cand_k[ci];
                const float* crow = codebook + (size_t)k * D_SZ;
                double sum = 0.0;
#pragma unroll
                for (int j = 0; j < D_SZ / 64; j++)
                    sum += rres[lane + 64 * j] * (double)crow[lane + 64 * j];
#pragma unroll
                for (int o = 32; o > 0; o >>= 1) sum += __shfl_down(sum, o, 64);
                if (lane == 0) cand_v[ci] = sum;
            }
        }
        __syncthreads();

        if (tid == 0) {
            int bk = cand_k[0]; double bv = cand_v[0];
            for (int c = 1; c < nc; c++) {
                int k2 = cand_k[c]; double v2 = cand_v[c];
                if (fabs(v2) > fabs(bv) || (fabs(v2) == fabs(bv) && k2 < bk)) { bk = k2; bv = v2; }
            }
            double sgn = (bv >= 0.0) ? 1.0 : -1.0;
            s_best = bk;
            s_sd = sgn * decay;
            int signed_idx = (bv >= 0.0) ? bk : (-bk - 1);
            out_seq[(size_t)b * L_SZ + t]  = (float)signed_idx;
            out_mask[(size_t)b * L_SZ + t] = 1.0f;
        }
        __syncthreads();
        const int bk = s_best;
        const double sd = s_sd;
        const float sdf = (float)sd;

        // approx score update with Gram row (fp32)
        const float* Grow = S + (size_t)(B_SZ + bk) * K_SZ;
#pragma unroll
        for (int j = 0; j < K_SZ / 256; j++) {
            int k = tid + 256 * j;
            g[k] -= sdf * Grow[k];
        }
        // exact residual update + exact ||r||^2 (fp64)
        const float* crow = codebook + (size_t)bk * D_SZ;
        double rl = 0.0;
        for (int i = tid; i < D_SZ; i += 256) {
            double nv = rres[i] - sd * (double)crow[i];
            rres[i] = nv;
            rl += nv * nv;
        }
#pragma unroll
        for (int o = 32; o > 0; o >>= 1) rl += __shfl_down(rl, o, 64);
        if (lane == 0) redD[wave] = rl;
        __syncthreads();
        rn2 = redD[0] + redD[1] + redD[2] + redD[3];
        __syncthreads();
    }

    // final residual (fp32)
    for (int i = tid; i < D_SZ; i += 256)
        out_res[(size_t)b * D_SZ + i] = (float)rres[i];
}

// ---------------------------------------------------------------------------
extern "C" void kernel_launch(void* const* d_in, const int* in_sizes, int n_in,
                              void* d_out, int out_size, void* d_ws, size_t ws_size,
                              hipStream_t stream) {
    const float* targets  = (const float*)d_in[0];
    const float* codebook = (const float*)d_in[1];
    float* out = (float*)d_out;

    __hip_bfloat16* abf = (__hip_bfloat16*)d_ws;                        // 12,582,912 B
    float* S = (float*)((char*)d_ws + (size_t)M_ALL * D_SZ * 2);        // 201,326,592 B
    // total ws needed: 213,909,504 B

    int total4 = (M_ALL * D_SZ) / 4;
    cast_bf16_kernel<<<(total4 + 255) / 256, 256, 0, stream>>>(targets, codebook, abf);

    dim3 ggrid(K_SZ / BN, M_ALL / BM);
    gemm_bt_kernel<<<ggrid, 256, 0, stream>>>(abf, abf + (size_t)B_SZ * D_SZ, S);

    pursuit_kernel<<<B_SZ, 256, 0, stream>>>(targets, codebook, S, out);
}

// Round 2
// 396.407 us; speedup vs baseline: 1.4360x; 1.4360x over previous
//
#include <hip/hip_runtime.h>
#include <hip/hip_bf16.h>

// Problem constants
#define B_SZ 8192
#define D_SZ 512
#define K_SZ 4096
#define L_SZ 16
#define M_ALL (B_SZ + K_SZ)   // 12288 rows: targets stacked over codebook

typedef __attribute__((ext_vector_type(8))) short short8v;      // 8 bf16
typedef __attribute__((ext_vector_type(4))) float f32x4;
typedef _Float16 half8v __attribute__((ext_vector_type(8)));    // 8 fp16 = 16B

// ---------------------------------------------------------------------------
// Kernel 1: cast targets+codebook (fp32) into one stacked bf16 matrix [12288 x 512]
// ---------------------------------------------------------------------------
__global__ void cast_bf16_kernel(const float* __restrict__ targets,
                                 const float* __restrict__ codebook,
                                 __hip_bfloat16* __restrict__ abf) {
    int idx = blockIdx.x * blockDim.x + threadIdx.x;
    const int total4 = (M_ALL * D_SZ) / 4;
    if (idx >= total4) return;
    int base = idx * 4;
    const float* src = (base < B_SZ * D_SZ) ? (targets + base)
                                            : (codebook + (base - B_SZ * D_SZ));
    float4 v = *(const float4*)src;
    abf[base + 0] = __float2bfloat16(v.x);
    abf[base + 1] = __float2bfloat16(v.y);
    abf[base + 2] = __float2bfloat16(v.z);
    abf[base + 3] = __float2bfloat16(v.w);
}

// ---------------------------------------------------------------------------
// Kernel 1b: exact fp64 codebook row norms^2 (for algebraic ||r||^2 update)
// ---------------------------------------------------------------------------
__global__ void cn2_kernel(const float* __restrict__ codebook,
                           double* __restrict__ cn2) {
    int row  = blockIdx.x * 4 + (threadIdx.x >> 6);
    int lane = threadIdx.x & 63;
    const float* r = codebook + (size_t)row * D_SZ;
    double s = 0.0;
#pragma unroll
    for (int j = 0; j < 8; j++) { double v = (double)r[lane + 64 * j]; s += v * v; }
#pragma unroll
    for (int o = 32; o > 0; o >>= 1) s += __shfl_down(s, o, 64);
    if (lane == 0) cn2[row] = s;
}

// ---------------------------------------------------------------------------
// Kernel 2: S = A * B^T -> fp16 [M x 4096]. 128x128 tile, 4 waves, 16x16x32 MFMA.
// ---------------------------------------------------------------------------
#define BM 128
#define BN 128
#define BK 32
#define LDSS 40

__global__ __launch_bounds__(256, 2)
void gemm_bt_kernel(const __hip_bfloat16* __restrict__ A,
                    const __hip_bfloat16* __restrict__ Bm,
                    _Float16* __restrict__ C) {
    __shared__ short As[BM * LDSS];
    __shared__ short Bs[BN * LDSS];
    const int tid  = threadIdx.x;
    const int bm   = blockIdx.y * BM;
    const int bn   = blockIdx.x * BN;
    const int wave = tid >> 6, lane = tid & 63;
    const int wm = (wave & 1) * 64, wn = (wave >> 1) * 64;
    const int row16 = lane & 15, quad = lane >> 4;
    const int koff = quad * 8;

    f32x4 acc[4][4] = {};

    const int srow = tid >> 1;
    const int scol = (tid & 1) * 16;
    const short* Ag = (const short*)A;
    const short* Bg = (const short*)Bm;

    for (int k0 = 0; k0 < D_SZ; k0 += BK) {
        short8v a0 = *(const short8v*)(Ag + (size_t)(bm + srow) * D_SZ + k0 + scol);
        short8v a1 = *(const short8v*)(Ag + (size_t)(bm + srow) * D_SZ + k0 + scol + 8);
        short8v b0 = *(const short8v*)(Bg + (size_t)(bn + srow) * D_SZ + k0 + scol);
        short8v b1 = *(const short8v*)(Bg + (size_t)(bn + srow) * D_SZ + k0 + scol + 8);
        __syncthreads();
        *(short8v*)(As + srow * LDSS + scol)     = a0;
        *(short8v*)(As + srow * LDSS + scol + 8) = a1;
        *(short8v*)(Bs + srow * LDSS + scol)     = b0;
        *(short8v*)(Bs + srow * LDSS + scol + 8) = b1;
        __syncthreads();

        short8v af[4], bf[4];
#pragma unroll
        for (int i = 0; i < 4; i++)
            af[i] = *(const short8v*)(As + (wm + i * 16 + row16) * LDSS + koff);
#pragma unroll
        for (int j = 0; j < 4; j++)
            bf[j] = *(const short8v*)(Bs + (wn + j * 16 + row16) * LDSS + koff);
#pragma unroll
        for (int i = 0; i < 4; i++)
#pragma unroll
            for (int j = 0; j < 4; j++)
                acc[i][j] = __builtin_amdgcn_mfma_f32_16x16x32_bf16(af[i], bf[j], acc[i][j], 0, 0, 0);
    }

#pragma unroll
    for (int i = 0; i < 4; i++) {
        int grow = bm + wm + i * 16 + quad * 4;
#pragma unroll
        for (int j = 0; j < 4; j++) {
            int gcol = bn + wn + j * 16 + row16;
#pragma unroll
            for (int r = 0; r < 4; r++)
                C[(size_t)(grow + r) * K_SZ + gcol] = (_Float16)acc[i][j][r];
        }
    }
}

// ---------------------------------------------------------------------------
// Kernel 3: pursuit. One block (256 thr) per batch row. g in REGISTERS
// (16 fp32/thread, thread owns k = j*2048 + 8*tid + e). Exact fp64 residual
// in LDS; exact rescore of margin candidates; algebraic ||r||^2 update.
// ---------------------------------------------------------------------------
#define MAXC 64
#define MARGIN 2.0f

__global__ __launch_bounds__(256, 4)
void pursuit_kernel(const float* __restrict__ targets,
                    const float* __restrict__ codebook,
                    const _Float16* __restrict__ S,   // [12288 x 4096]; rows >=8192 are Gram
                    const double* __restrict__ cn2,   // [4096] exact ||c_k||^2
                    float* __restrict__ out) {
    const int b = blockIdx.x;
    const int tid = threadIdx.x;
    const int lane = tid & 63, wave = tid >> 6;

    __shared__ double rres[D_SZ];
    __shared__ double redD[4];
    __shared__ float  redF[4];
    __shared__ int    cand_k[MAXC];
    __shared__ double cand_v[MAXC];
    __shared__ int    ncand;
    __shared__ int    s_best;
    __shared__ double s_sd;
    __shared__ double s_rn2;

    // ---- init: g regs from fp16 score row (2x 16B vector loads) ----
    float g_r[16];
    {
        const _Float16* g0 = S + (size_t)b * K_SZ;
#pragma unroll
        for (int j = 0; j < 2; j++) {
            half8v h = *(const half8v*)(g0 + j * 2048 + 8 * tid);
#pragma unroll
            for (int e = 0; e < 8; e++) g_r[8 * j + e] = (float)h[e];
        }
    }

    // ---- residual = target (fp64) + tn2 ----
    double loc = 0.0;
#pragma unroll
    for (int j = 0; j < 2; j++) {
        int i = tid + 256 * j;
        double v = (double)targets[(size_t)b * D_SZ + i];
        rres[i] = v;
        loc += v * v;
    }
#pragma unroll
    for (int o = 32; o > 0; o >>= 1) loc += __shfl_down(loc, o, 64);
    if (lane == 0) redD[wave] = loc;
    __syncthreads();
    const double tn2 = redD[0] + redD[1] + redD[2] + redD[3];
    if (tid == 0) s_rn2 = tn2;
    __syncthreads();
    const bool tgt_ok = (sqrt(tn2) >= 1e-8);

    float* out_seq  = out;
    float* out_mask = out + (size_t)B_SZ * L_SZ;
    float* out_res  = out + (size_t)2 * B_SZ * L_SZ;

    double decay = 1.0;
    for (int t = 0; t < L_SZ; t++) {
        decay *= 0.95;
        double rn2 = s_rn2;                       // written by tid0 pre-B4 of prev step
        bool active = (sqrt(rn2) >= 0.01) && tgt_ok;
        if (!active) {                            // block-uniform branch
            if (tid == 0) {
                out_seq[(size_t)b * L_SZ + t]  = 0.0f;
                out_mask[(size_t)b * L_SZ + t] = 0.0f;
            }
            continue;
        }

        // ---- approx max |g| (registers -> wave shuffle -> LDS) ----
        float m = 0.0f;
#pragma unroll
        for (int j = 0; j < 16; j++) m = fmaxf(m, fabsf(g_r[j]));
#pragma unroll
        for (int o = 32; o > 0; o >>= 1) m = fmaxf(m, __shfl_down(m, o, 64));
        if (lane == 0) redF[wave] = m;
        if (tid == 0) ncand = 0;
        __syncthreads();                          // B1
        float M = fmaxf(fmaxf(redF[0], redF[1]), fmaxf(redF[2], redF[3]));
        float thr = M - MARGIN;

        // ---- candidate collection from registers ----
#pragma unroll
        for (int j = 0; j < 2; j++)
#pragma unroll
            for (int e = 0; e < 8; e++) {
                if (fabsf(g_r[8 * j + e]) >= thr) {
                    int p = atomicAdd(&ncand, 1);
                    if (p < MAXC) cand_k[p] = j * 2048 + 8 * tid + e;
                }
            }
        __syncthreads();                          // B2
        int nc = min(ncand, MAXC);

        // ---- exact fp64 rescore: one wave per candidate ----
        for (int ci = wave; ci < nc; ci += 4) {
            int k = cand_k[ci];
            const float* crow = codebook + (size_t)k * D_SZ;
            double sum = 0.0;
#pragma unroll
            for (int j = 0; j < 8; j++)
                sum += rres[lane + 64 * j] * (double)crow[lane + 64 * j];
#pragma unroll
            for (int o = 32; o > 0; o >>= 1) sum += __shfl_down(sum, o, 64);
            if (lane == 0) cand_v[ci] = sum;
        }
        __syncthreads();                          // B3

        if (tid == 0) {
            int bk = cand_k[0]; double bv = cand_v[0];
            for (int c = 1; c < nc; c++) {
                int k2 = cand_k[c]; double v2 = cand_v[c];
                if (fabs(v2) > fabs(bv) || (fabs(v2) == fabs(bv) && k2 < bk)) { bk = k2; bv = v2; }
            }
            double sd = ((bv >= 0.0) ? 1.0 : -1.0) * decay;
            s_best = bk;
            s_sd = sd;
            s_rn2 = rn2 - 2.0 * sd * bv + sd * sd * cn2[bk];   // exact identity
            out_seq[(size_t)b * L_SZ + t]  = (float)((bv >= 0.0) ? bk : (-bk - 1));
            out_mask[(size_t)b * L_SZ + t] = 1.0f;
        }
        __syncthreads();                          // B4
        const int bk = s_best;
        const double sd = s_sd;
        const float sdf = (float)sd;

        // ---- approx score update: fp16 Gram row, 2x 16B vector loads ----
        const _Float16* Grow = S + (size_t)(B_SZ + bk) * K_SZ;
#pragma unroll
        for (int j = 0; j < 2; j++) {
            half8v h = *(const half8v*)(Grow + j * 2048 + 8 * tid);
#pragma unroll
            for (int e = 0; e < 8; e++) g_r[8 * j + e] -= sdf * (float)h[e];
        }
        // ---- exact residual update (owner threads; no cross-thread read here) ----
        const float* crow = codebook + (size_t)bk * D_SZ;
#pragma unroll
        for (int j = 0; j < 2; j++) {
            int i = tid + 256 * j;
            rres[i] = rres[i] - sd * (double)crow[i];
        }
        // next iteration's rescore reads rres only after B1+B2 -> ordered
    }

    // ---- final residual (each thread wrote these same entries) ----
#pragma unroll
    for (int j = 0; j < 2; j++) {
        int i = tid + 256 * j;
        out_res[(size_t)b * D_SZ + i] = (float)rres[i];
    }
}

// ---------------------------------------------------------------------------
extern "C" void kernel_launch(void* const* d_in, const int* in_sizes, int n_in,
                              void* d_out, int out_size, void* d_ws, size_t ws_size,
                              hipStream_t stream) {
    const float* targets  = (const float*)d_in[0];
    const float* codebook = (const float*)d_in[1];
    float* out = (float*)d_out;

    __hip_bfloat16* abf = (__hip_bfloat16*)d_ws;                         // 12,582,912 B
    _Float16* S = (_Float16*)((char*)d_ws + (size_t)M_ALL * D_SZ * 2);   // 100,663,296 B
    double* cn2 = (double*)((char*)d_ws + (size_t)M_ALL * D_SZ * 2
                                        + (size_t)M_ALL * K_SZ * 2);     // 32,768 B
    // total ws needed: ~113.3 MB

    int total4 = (M_ALL * D_SZ) / 4;
    cast_bf16_kernel<<<(total4 + 255) / 256, 256, 0, stream>>>(targets, codebook, abf);
    cn2_kernel<<<K_SZ / 4, 256, 0, stream>>>(codebook, cn2);

    dim3 ggrid(K_SZ / BN, M_ALL / BM);
    gemm_bt_kernel<<<ggrid, 256, 0, stream>>>(abf, abf + (size_t)B_SZ * D_SZ, S);

    pursuit_kernel<<<B_SZ, 256, 0, stream>>>(targets, codebook, S, cn2, out);
}

// Round 3
// 382.803 us; speedup vs baseline: 1.4870x; 1.0355x over previous
//
#include <hip/hip_runtime.h>
#include <hip/hip_bf16.h>

// Problem constants
#define B_SZ 8192
#define D_SZ 512
#define K_SZ 4096
#define L_SZ 16
#define M_ALL (B_SZ + K_SZ)   // 12288 rows: targets stacked over codebook

typedef __attribute__((ext_vector_type(8))) short short8v;      // 8 bf16
typedef __attribute__((ext_vector_type(4))) float f32x4;
typedef _Float16 half8v __attribute__((ext_vector_type(8)));    // 8 fp16 = 16B

// ---------------------------------------------------------------------------
// Kernel 1: cast targets+codebook (fp32) into one stacked bf16 matrix [12288 x 512]
// ---------------------------------------------------------------------------
__global__ void cast_bf16_kernel(const float* __restrict__ targets,
                                 const float* __restrict__ codebook,
                                 __hip_bfloat16* __restrict__ abf) {
    int idx = blockIdx.x * blockDim.x + threadIdx.x;
    const int total4 = (M_ALL * D_SZ) / 4;
    if (idx >= total4) return;
    int base = idx * 4;
    const float* src = (base < B_SZ * D_SZ) ? (targets + base)
                                            : (codebook + (base - B_SZ * D_SZ));
    float4 v = *(const float4*)src;
    abf[base + 0] = __float2bfloat16(v.x);
    abf[base + 1] = __float2bfloat16(v.y);
    abf[base + 2] = __float2bfloat16(v.z);
    abf[base + 3] = __float2bfloat16(v.w);
}

// ---------------------------------------------------------------------------
// Kernel 1b: exact fp64 codebook row norms^2 (for algebraic ||r||^2 update)
// ---------------------------------------------------------------------------
__global__ void cn2_kernel(const float* __restrict__ codebook,
                           double* __restrict__ cn2) {
    int row  = blockIdx.x * 4 + (threadIdx.x >> 6);
    int lane = threadIdx.x & 63;
    const float* r = codebook + (size_t)row * D_SZ;
    double s = 0.0;
#pragma unroll
    for (int j = 0; j < 8; j++) { double v = (double)r[lane + 64 * j]; s += v * v; }
#pragma unroll
    for (int o = 32; o > 0; o >>= 1) s += __shfl_down(s, o, 64);
    if (lane == 0) cn2[row] = s;
}

// ---------------------------------------------------------------------------
// Kernel 2: S = A * B^T -> fp16 [M x 4096]. 128x128 tile, 4 waves, 16x16x32 MFMA.
// ---------------------------------------------------------------------------
#define BM 128
#define BN 128
#define BK 32
#define LDSS 40

__global__ __launch_bounds__(256, 2)
void gemm_bt_kernel(const __hip_bfloat16* __restrict__ A,
                    const __hip_bfloat16* __restrict__ Bm,
                    _Float16* __restrict__ C) {
    __shared__ short As[BM * LDSS];
    __shared__ short Bs[BN * LDSS];
    const int tid  = threadIdx.x;
    const int bm   = blockIdx.y * BM;
    const int bn   = blockIdx.x * BN;
    const int wave = tid >> 6, lane = tid & 63;
    const int wm = (wave & 1) * 64, wn = (wave >> 1) * 64;
    const int row16 = lane & 15, quad = lane >> 4;
    const int koff = quad * 8;

    f32x4 acc[4][4] = {};

    const int srow = tid >> 1;
    const int scol = (tid & 1) * 16;
    const short* Ag = (const short*)A;
    const short* Bg = (const short*)Bm;

    for (int k0 = 0; k0 < D_SZ; k0 += BK) {
        short8v a0 = *(const short8v*)(Ag + (size_t)(bm + srow) * D_SZ + k0 + scol);
        short8v a1 = *(const short8v*)(Ag + (size_t)(bm + srow) * D_SZ + k0 + scol + 8);
        short8v b0 = *(const short8v*)(Bg + (size_t)(bn + srow) * D_SZ + k0 + scol);
        short8v b1 = *(const short8v*)(Bg + (size_t)(bn + srow) * D_SZ + k0 + scol + 8);
        __syncthreads();
        *(short8v*)(As + srow * LDSS + scol)     = a0;
        *(short8v*)(As + srow * LDSS + scol + 8) = a1;
        *(short8v*)(Bs + srow * LDSS + scol)     = b0;
        *(short8v*)(Bs + srow * LDSS + scol + 8) = b1;
        __syncthreads();

        short8v af[4], bf[4];
#pragma unroll
        for (int i = 0; i < 4; i++)
            af[i] = *(const short8v*)(As + (wm + i * 16 + row16) * LDSS + koff);
#pragma unroll
        for (int j = 0; j < 4; j++)
            bf[j] = *(const short8v*)(Bs + (wn + j * 16 + row16) * LDSS + koff);
#pragma unroll
        for (int i = 0; i < 4; i++)
#pragma unroll
            for (int j = 0; j < 4; j++)
                acc[i][j] = __builtin_amdgcn_mfma_f32_16x16x32_bf16(af[i], bf[j], acc[i][j], 0, 0, 0);
    }

#pragma unroll
    for (int i = 0; i < 4; i++) {
        int grow = bm + wm + i * 16 + quad * 4;
#pragma unroll
        for (int j = 0; j < 4; j++) {
            int gcol = bn + wn + j * 16 + row16;
#pragma unroll
            for (int r = 0; r < 4; r++)
                C[(size_t)(grow + r) * K_SZ + gcol] = (_Float16)acc[i][j][r];
        }
    }
}

// ---------------------------------------------------------------------------
// Kernel 3: pursuit, wave-per-row, barrier-free.
// Lane owns: g[64] fp32 regs (k = jb*512 + lane*8 + e), rres[8] fp64 regs
// (i = lane*8 + e; lane-private in BOTH rescore and update). Cross-lane only
// via shfl_xor butterflies (bit-identical results on all lanes). Only LDS:
// per-wave candidate list.
// ---------------------------------------------------------------------------
#define MAXC 32
#define MARGIN 1.0f

__global__ __launch_bounds__(256, 4)
void pursuit_kernel(const float* __restrict__ targets,
                    const float* __restrict__ codebook,
                    const _Float16* __restrict__ S,   // [12288 x 4096]; rows >=8192 are Gram
                    const double* __restrict__ cn2,   // [4096] exact ||c_k||^2
                    float* __restrict__ out) {
    const int wave = threadIdx.x >> 6;
    const int lane = threadIdx.x & 63;
    const int b = blockIdx.x * 4 + wave;
    const int lane8 = lane * 8;

    __shared__ int s_cnt[4];
    __shared__ int s_cand[4][MAXC];
    int* cnt  = &s_cnt[wave];
    int* cand = s_cand[wave];

    // ---- g regs from fp16 score row ----
    float g_r[64];
    {
        const _Float16* g0 = S + (size_t)b * K_SZ + lane8;
#pragma unroll
        for (int jb = 0; jb < 8; jb++) {
            half8v h = *(const half8v*)(g0 + jb * 512);
#pragma unroll
            for (int e = 0; e < 8; e++) g_r[jb * 8 + e] = (float)h[e];
        }
    }

    // ---- lane-private fp64 residual + tn2 ----
    double rres[8];
    double loc = 0.0;
    {
        const float* tg = targets + (size_t)b * D_SZ + lane8;
        float4 t0 = *(const float4*)tg;
        float4 t1 = *(const float4*)(tg + 4);
        rres[0] = t0.x; rres[1] = t0.y; rres[2] = t0.z; rres[3] = t0.w;
        rres[4] = t1.x; rres[5] = t1.y; rres[6] = t1.z; rres[7] = t1.w;
#pragma unroll
        for (int e = 0; e < 8; e++) loc += rres[e] * rres[e];
    }
#pragma unroll
    for (int o = 32; o > 0; o >>= 1) loc += __shfl_xor(loc, o, 64);
    const double tn2 = loc;                      // identical on all lanes
    double rn2 = tn2;
    const bool tgt_ok = (sqrt(tn2) >= 1e-8);

    float* out_seq  = out;
    float* out_mask = out + (size_t)B_SZ * L_SZ;
    float* out_res  = out + (size_t)2 * B_SZ * L_SZ;

    double decay = 1.0;
    for (int t = 0; t < L_SZ; t++) {
        decay *= 0.95;
        bool active = (sqrt(rn2) >= 0.01) && tgt_ok;   // wave-uniform
        if (!active) {
            if (lane == 0) {
                out_seq[(size_t)b * L_SZ + t]  = 0.0f;
                out_mask[(size_t)b * L_SZ + t] = 0.0f;
            }
            continue;
        }

        // ---- approx max |g|: 64 regs -> butterfly (all lanes get M) ----
        float m = 0.0f;
#pragma unroll
        for (int j = 0; j < 64; j++) m = fmaxf(m, fabsf(g_r[j]));
        float M = m;
#pragma unroll
        for (int o = 32; o > 0; o >>= 1) M = fmaxf(M, __shfl_xor(M, o, 64));
        float thr = M - MARGIN;

        // ---- candidate collection (per-wave LDS list; same-wave DS in-order) ----
        if (lane == 0) *cnt = 0;
        if (m >= thr) {                          // only lanes that can hold one
#pragma unroll
            for (int jb = 0; jb < 8; jb++)
#pragma unroll
                for (int e = 0; e < 8; e++)
                    if (fabsf(g_r[jb * 8 + e]) >= thr) {
                        int p = atomicAdd(cnt, 1);
                        if (p < MAXC) cand[p] = jb * 512 + lane8 + e;
                    }
        }
        __threadfence_block();
        int nc = min(*cnt, MAXC);

        // ---- exact fp64 rescore of each candidate (whole wave per candidate) ----
        int bk = -1; double bv = 0.0; bool have = false;
        for (int ci = 0; ci < nc; ci++) {
            int k = cand[ci];                    // same-address broadcast read
            const float* crow = codebook + (size_t)k * D_SZ + lane8;
            float4 c0 = *(const float4*)crow;
            float4 c1 = *(const float4*)(crow + 4);
            double s = rres[0] * (double)c0.x + rres[1] * (double)c0.y
                     + rres[2] * (double)c0.z + rres[3] * (double)c0.w
                     + rres[4] * (double)c1.x + rres[5] * (double)c1.y
                     + rres[6] * (double)c1.z + rres[7] * (double)c1.w;
#pragma unroll
            for (int o = 32; o > 0; o >>= 1) s += __shfl_xor(s, o, 64);
            // s identical on all lanes (butterfly is symmetric)
            if (!have || fabs(s) > fabs(bv) ||
                (fabs(s) == fabs(bv) && k < bk)) { bk = k; bv = s; have = true; }
        }

        // ---- decision + algebraic exact ||r||^2 update (wave-uniform) ----
        double sd = ((bv >= 0.0) ? 1.0 : -1.0) * decay;
        rn2 = rn2 - 2.0 * sd * bv + sd * sd * cn2[bk];
        if (lane == 0) {
            out_seq[(size_t)b * L_SZ + t]  = (float)((bv >= 0.0) ? bk : (-bk - 1));
            out_mask[(size_t)b * L_SZ + t] = 1.0f;
        }
        const float sdf = (float)sd;

        // ---- approx score update with fp16 Gram row ----
        const _Float16* Grow = S + (size_t)(B_SZ + bk) * K_SZ + lane8;
#pragma unroll
        for (int jb = 0; jb < 8; jb++) {
            half8v h = *(const half8v*)(Grow + jb * 512);
#pragma unroll
            for (int e = 0; e < 8; e++) g_r[jb * 8 + e] -= sdf * (float)h[e];
        }
        // ---- exact lane-private residual update ----
        const float* crow = codebook + (size_t)bk * D_SZ + lane8;
        {
            float4 c0 = *(const float4*)crow;
            float4 c1 = *(const float4*)(crow + 4);
            rres[0] -= sd * (double)c0.x; rres[1] -= sd * (double)c0.y;
            rres[2] -= sd * (double)c0.z; rres[3] -= sd * (double)c0.w;
            rres[4] -= sd * (double)c1.x; rres[5] -= sd * (double)c1.y;
            rres[6] -= sd * (double)c1.z; rres[7] -= sd * (double)c1.w;
        }
    }

    // ---- final residual ----
    {
        float* o = out_res + (size_t)b * D_SZ + lane8;
        float4 r0, r1;
        r0.x = (float)rres[0]; r0.y = (float)rres[1]; r0.z = (float)rres[2]; r0.w = (float)rres[3];
        r1.x = (float)rres[4]; r1.y = (float)rres[5]; r1.z = (float)rres[6]; r1.w = (float)rres[7];
        *(float4*)o = r0;
        *(float4*)(o + 4) = r1;
    }
}

// ---------------------------------------------------------------------------
extern "C" void kernel_launch(void* const* d_in, const int* in_sizes, int n_in,
                              void* d_out, int out_size, void* d_ws, size_t ws_size,
                              hipStream_t stream) {
    const float* targets  = (const float*)d_in[0];
    const float* codebook = (const float*)d_in[1];
    float* out = (float*)d_out;

    __hip_bfloat16* abf = (__hip_bfloat16*)d_ws;                         // 12,582,912 B
    _Float16* S = (_Float16*)((char*)d_ws + (size_t)M_ALL * D_SZ * 2);   // 100,663,296 B
    double* cn2 = (double*)((char*)d_ws + (size_t)M_ALL * D_SZ * 2
                                        + (size_t)M_ALL * K_SZ * 2);     // 32,768 B
    // total ws needed: ~113.3 MB

    int total4 = (M_ALL * D_SZ) / 4;
    cast_bf16_kernel<<<(total4 + 255) / 256, 256, 0, stream>>>(targets, codebook, abf);
    cn2_kernel<<<K_SZ / 4, 256, 0, stream>>>(codebook, cn2);

    dim3 ggrid(K_SZ / BN, M_ALL / BM);
    gemm_bt_kernel<<<ggrid, 256, 0, stream>>>(abf, abf + (size_t)B_SZ * D_SZ, S);

    pursuit_kernel<<<B_SZ / 4, 256, 0, stream>>>(targets, codebook, S, cn2, out);
}